// Round 6
// baseline (582.001 us; speedup 1.0000x reference)
//
#include <hip/hip_runtime.h>

#define D 256

typedef __attribute__((ext_vector_type(8))) short s16x8;
typedef __attribute__((ext_vector_type(4))) float f32x4;

static __device__ __forceinline__ unsigned short f2b(float f) {
    unsigned u = __float_as_uint(f);
    unsigned r = (u + 0x7fffu + ((u >> 16) & 1u)) >> 16;   // RNE
    return (unsigned short)r;
}
static __device__ __forceinline__ unsigned pack2(float a, float b) {
    return (unsigned)f2b(a) | ((unsigned)f2b(b) << 16);
}

// async global->LDS, 16B per lane; LDS dest is wave-uniform base + lane*16
static __device__ __forceinline__ void gload_lds16(const void* g, void* l) {
    __builtin_amdgcn_global_load_lds((const __attribute__((address_space(1))) unsigned int*)g,
                                     (__attribute__((address_space(3))) unsigned int*)l,
                                     16, 0, 0);
}

// ---- fused: cast vrepr to bf16 (blocks < nvb) + cast both weight matrices to
// MFMA B-fragment order (blocks >= nvb).
// Fragment layout (16x16x32 bf16): tile t (16 rows), k-tile kt (32 k),
// lane l = (row&15) | (((k>>3)&3)<<4) holds 8 contiguous bf16.
// unit index (16B units) = (t<<9) + (kt<<6) + lane.
__global__ void prep_conv_kernel(const float* __restrict__ vr,
                                 const float* __restrict__ lw, const float* __restrict__ sw,
                                 unsigned short* __restrict__ vb,
                                 unsigned short* __restrict__ wTf, int n8, int nvb) {
    if ((int)blockIdx.x < nvb) {
        int i = blockIdx.x * 256 + threadIdx.x;
        if (i < n8) {
            float4 f0 = ((const float4*)vr)[2 * i];
            float4 f1 = ((const float4*)vr)[2 * i + 1];
            uint4 o;
            o.x = pack2(f0.x, f0.y);
            o.y = pack2(f0.z, f0.w);
            o.z = pack2(f1.x, f1.y);
            o.w = pack2(f1.z, f1.w);
            ((uint4*)vb)[i] = o;
        }
    } else {
        // 2*D*D elements, 4 per thread, 4-aligned: same n, same k>>3 group
        int i = (blockIdx.x - nvb) * 256 + threadIdx.x;
        int e0 = i * 4;
        if (e0 < 2 * D * D) {
            const float* src = (e0 < D * D) ? (lw + e0) : (sw + (e0 - D * D));
            float4 f = *(const float4*)src;
            int n = e0 >> 8;         // 0..511: concatenated [loc; std] col
            int k0 = e0 & 255;
            int lane = (n & 15) | (((k0 >> 3) & 3) << 4);
            int unit = ((n >> 4) << 9) + ((k0 >> 5) << 6) + lane;
            uint2 o;
            o.x = pack2(f.x, f.y);
            o.y = pack2(f.z, f.w);
            *(uint2*)&wTf[unit * 8 + (k0 & 7)] = o;
        }
    }
}

// ---- histogram of target indices; records each edge's arrival rank ----
__global__ void hist_kernel(const int* __restrict__ tidx, int* __restrict__ cnt,
                            int* __restrict__ rank, int E) {
    int e = blockIdx.x * blockDim.x + threadIdx.x;
    if (e < E) rank[e] = atomicAdd(&cnt[tidx[e]], 1);
}

// ---- hierarchical scan: 49 blocks x 1024 elems -> 1 block -> 49 blocks ----
__global__ void scan1_kernel(const int* __restrict__ cnt, int* __restrict__ bsum, int V) {
    __shared__ int red[256];
    int b = blockIdx.x, tid = threadIdx.x;
    int base = b * 1024 + tid * 4;
    int s = 0;
    if (base + 3 < V) {
        int4 q = *(const int4*)&cnt[base];
        s = q.x + q.y + q.z + q.w;
    } else {
        for (int j = 0; j < 4; ++j)
            if (base + j < V) s += cnt[base + j];
    }
    red[tid] = s;
    __syncthreads();
    for (int ofs = 128; ofs > 0; ofs >>= 1) {
        if (tid < ofs) red[tid] += red[tid + ofs];
        __syncthreads();
    }
    if (tid == 0) bsum[b] = red[0];
}

__global__ void scan2_kernel(int* __restrict__ bsum, int nb) {
    __shared__ int s[256];
    int tid = threadIdx.x;
    int v = (tid < nb) ? bsum[tid] : 0;
    s[tid] = v;
    __syncthreads();
    for (int ofs = 1; ofs < 256; ofs <<= 1) {
        int t = (tid >= ofs) ? s[tid - ofs] : 0;
        __syncthreads();
        s[tid] += t;
        __syncthreads();
    }
    if (tid < nb) bsum[tid] = s[tid] - v;   // exclusive
}

__global__ void scan3_kernel(const int* __restrict__ cnt, const int* __restrict__ bsum,
                             int* __restrict__ off, int V, int E) {
    __shared__ int ts[256];
    int b = blockIdx.x, tid = threadIdx.x;
    int base = b * 1024 + tid * 4;
    int v0 = 0, v1 = 0, v2 = 0, v3 = 0;
    if (base + 3 < V) {
        int4 q = *(const int4*)&cnt[base];
        v0 = q.x; v1 = q.y; v2 = q.z; v3 = q.w;
    } else {
        if (base < V)     v0 = cnt[base];
        if (base + 1 < V) v1 = cnt[base + 1];
        if (base + 2 < V) v2 = cnt[base + 2];
        if (base + 3 < V) v3 = cnt[base + 3];
    }
    int tsum = v0 + v1 + v2 + v3;
    ts[tid] = tsum;
    __syncthreads();
    for (int ofs = 1; ofs < 256; ofs <<= 1) {
        int t = (tid >= ofs) ? ts[tid - ofs] : 0;
        __syncthreads();
        ts[tid] += t;
        __syncthreads();
    }
    int pre = bsum[b] + ts[tid] - tsum;
    if (base + 3 < V) {
        int4 o = make_int4(pre, pre + v0, pre + v0 + v1, pre + v0 + v1 + v2);
        *(int4*)&off[base] = o;
    } else {
        if (base < V)     off[base] = pre;
        if (base + 1 < V) off[base + 1] = pre + v0;
        if (base + 2 < V) off[base + 2] = pre + v0 + v1;
        if (base + 3 < V) off[base + 3] = pre + v0 + v1 + v2;
    }
    if (b == 0 && tid == 0) off[V] = E;
}

// ---- scatter edges into CSR buckets (atomic-free: off[t] + rank[e]) ----
// pk record = 8B: low 32 = sidx, high 32 = weight bits; stored nontemporal.
__global__ void fill_kernel(const int* __restrict__ sidx, const int* __restrict__ tidx,
                            const float* __restrict__ esgn, const float* __restrict__ enorm,
                            const int* __restrict__ off, const int* __restrict__ rank,
                            long long* __restrict__ pk, int E) {
    int e = blockIdx.x * blockDim.x + threadIdx.x;
    if (e >= E) return;
    int idx = off[tidx[e]] + rank[e];
    float w = enorm[e] * esgn[e];
    long long rec = (long long)(unsigned)sidx[e] |
                    ((long long)(unsigned)__float_as_uint(w) << 32);
    __builtin_nontemporal_store(rec, &pk[idx]);
}

#define FMA8(A, W)                                                   \
    acc[0] = fmaf(__uint_as_float((A).x << 16), (W), acc[0]);        \
    acc[1] = fmaf(__uint_as_float((A).x & 0xffff0000u), (W), acc[1]);\
    acc[2] = fmaf(__uint_as_float((A).y << 16), (W), acc[2]);        \
    acc[3] = fmaf(__uint_as_float((A).y & 0xffff0000u), (W), acc[3]);\
    acc[4] = fmaf(__uint_as_float((A).z << 16), (W), acc[4]);        \
    acc[5] = fmaf(__uint_as_float((A).z & 0xffff0000u), (W), acc[5]);\
    acc[6] = fmaf(__uint_as_float((A).w << 16), (W), acc[6]);        \
    acc[7] = fmaf(__uint_as_float((A).w & 0xffff0000u), (W), acc[7]);

// ---- one wave per target node: contiguous half-split, 4-deep gather chains ----
// pk loads nontemporal (streamed once; keep L2 for vb rows).
__global__ __launch_bounds__(256, 8) void accum_kernel(const unsigned short* __restrict__ vb,
                                                       const long long* __restrict__ pk,
                                                       const int* __restrict__ off,
                                                       unsigned short* __restrict__ ptrf, int V) {
    int gid = blockIdx.x * blockDim.x + threadIdx.x;
    int v = gid >> 6;
    if (v >= V) return;
    int lane = threadIdx.x & 63;
    int half = lane >> 5;     // each half-wave owns a contiguous range of edges
    int c = lane & 31;        // 16B chunk (8 bf16) within the row
    int beg = off[v], end = off[v + 1];
    int mid = beg + ((end - beg + 1) >> 1);
    int i = half ? mid : beg;
    int e = half ? end : mid;
    const uint4* base = (const uint4*)vb;   // row = 32 uint4
    float acc[8];
#pragma unroll
    for (int j = 0; j < 8; ++j) acc[j] = 0.f;
    for (; i + 3 < e; i += 4) {             // 4 independent gathers in flight
        long long r0 = __builtin_nontemporal_load(&pk[i]);
        long long r1 = __builtin_nontemporal_load(&pk[i + 1]);
        long long r2 = __builtin_nontemporal_load(&pk[i + 2]);
        long long r3 = __builtin_nontemporal_load(&pk[i + 3]);
        uint4 a0 = base[(size_t)(unsigned)r0 * 32 + c];
        uint4 a1 = base[(size_t)(unsigned)r1 * 32 + c];
        uint4 a2 = base[(size_t)(unsigned)r2 * 32 + c];
        uint4 a3 = base[(size_t)(unsigned)r3 * 32 + c];
        float w0 = __uint_as_float((unsigned)((unsigned long long)r0 >> 32));
        float w1 = __uint_as_float((unsigned)((unsigned long long)r1 >> 32));
        float w2 = __uint_as_float((unsigned)((unsigned long long)r2 >> 32));
        float w3 = __uint_as_float((unsigned)((unsigned long long)r3 >> 32));
        FMA8(a0, w0)
        FMA8(a1, w1)
        FMA8(a2, w2)
        FMA8(a3, w3)
    }
    for (; i < e; ++i) {
        long long r = __builtin_nontemporal_load(&pk[i]);
        float w = __uint_as_float((unsigned)((unsigned long long)r >> 32));
        uint4 a = base[(size_t)(unsigned)r * 32 + c];
        FMA8(a, w)
    }
#pragma unroll
    for (int j = 0; j < 8; ++j) acc[j] += __shfl_xor(acc[j], 32, 64);
    if (half == 0) {
        uint4 o;
        o.x = pack2(acc[0], acc[1]);
        o.y = pack2(acc[2], acc[3]);
        o.z = pack2(acc[4], acc[5]);
        o.w = pack2(acc[6], acc[7]);
        // A-fragment swizzled store: chunk c (k = 8c) of row v
        int fl = (v & 15) | ((c & 3) << 4);
        int unit = ((v >> 4) << 9) + ((c >> 2) << 6) + fl;
        ((uint4*)ptrf)[unit] = o;
    }
}

// ---- dual-head GEMM + bias + softplus + rsample, n-split across 2 blocks ----
// T3+T4: triple-buffered LDS staging with counted vmcnt (never 0 mid-loop) and
// raw s_barrier — stage loads stay in flight across barriers. Stage kt+2 is
// issued at iter kt; after issue, outstanding = stages kt+1,kt+2 = 8 loads, so
// s_waitcnt vmcnt(8) completes exactly stage kt. Compute consumes all ds_reads
// before the trailing barrier, so buffer (kt+2)%3 is free when restaged.
__global__ __launch_bounds__(256, 4) void head_mfma_kernel(const unsigned short* __restrict__ ptrf,
                                                           const unsigned short* __restrict__ wTf,
                                                           const float* __restrict__ lb,
                                                           const float* __restrict__ sb,
                                                           const float* __restrict__ eps,
                                                           float* __restrict__ out, int V) {
    __shared__ s16x8 Blds[3][1024];   // 3 x 16KB
    int tid = threadIdx.x;
    int wave = tid >> 6, lane = tid & 63;
    int nhalf = blockIdx.x;               // 0/1: which 128-col slice of each head
    int nb = nhalf << 3;                  // base n-tile within a head
    int mt = blockIdx.y * 4 + wave;       // m-tile = 16 rows
    int lastmt = (V - 1) >> 4;
    int mtc = mt > lastmt ? lastmt : mt;  // clamp: all waves stay for barriers
    int v0 = mt << 4;

    // A fragments: 8 x 16B per lane
    const s16x8* Af = (const s16x8*)ptrf + ((size_t)mtc << 9) + lane;
    s16x8 a[8];
#pragma unroll
    for (int kt = 0; kt < 8; ++kt) a[kt] = Af[kt << 6];

    const s16x8* Bf = (const s16x8*)wTf;

    f32x4 acc[16];
    f32x4 zero = {0.f, 0.f, 0.f, 0.f};
#pragma unroll
    for (int nt = 0; nt < 16; ++nt) acc[nt] = zero;

    // local n index ln 0..15 -> global n-tile: loc block then std block
#define STAGE_B(KT, BUF)                                                      \
    {                                                                         \
        _Pragma("unroll")                                                     \
        for (int j = 0; j < 4; ++j) {                                         \
            int ln = j * 4 + wave;                                            \
            int nt = (ln < 8) ? (nb + ln) : (16 + nb + (ln - 8));             \
            gload_lds16((const void*)(Bf + (nt << 9) + ((KT) << 6) + lane),   \
                        (void*)&Blds[BUF][ln << 6]);                          \
        }                                                                     \
    }

    STAGE_B(0, 0);
    STAGE_B(1, 1);

#pragma unroll
    for (int kt = 0; kt < 8; ++kt) {
        int buf = kt % 3;
        if (kt < 6) STAGE_B(kt + 2, (kt + 2) % 3);
        if (kt < 6)       asm volatile("s_waitcnt vmcnt(8)" ::: "memory");
        else if (kt == 6) asm volatile("s_waitcnt vmcnt(4)" ::: "memory");
        else              asm volatile("s_waitcnt vmcnt(0)" ::: "memory");
        __builtin_amdgcn_sched_barrier(0);
        __builtin_amdgcn_s_barrier();     // all waves' stage-kt writes visible
#pragma unroll
        for (int ln = 0; ln < 16; ++ln) {
            s16x8 b = Blds[buf][(ln << 6) + lane];
            acc[ln] = __builtin_amdgcn_mfma_f32_16x16x32_bf16(a[kt], b, acc[ln], 0, 0, 0);
        }
        if (kt < 7) __builtin_amdgcn_s_barrier();  // buffer free for restage
    }
#undef STAGE_B

    if (v0 < V) {   // V % 16 == 0: a live m-tile is always full
        int quad = lane >> 4, m16 = lane & 15;
        size_t VD = (size_t)V * D;
        const float* epsb = eps + (size_t)v0 * D;
        float* outb = out + (size_t)v0 * D;
#pragma unroll
        for (int ln = 0; ln < 8; ++ln) {
            int col = (nhalf << 7) + (ln << 4) + m16;
            float lbv = lb[col];
            float sbv = sb[col];
#pragma unroll
            for (int r = 0; r < 4; ++r) {
                int row = (quad << 2) + r;
                int o = row * D + col;
                float lo = acc[ln][r] + lbv;
                float pre = acc[ln + 8][r] + sbv;
                float sp = fmaxf(pre, 0.f) + __logf(1.f + __expf(-fabsf(pre)));
                float st = sp + 1e-7f;
                float ep = __builtin_nontemporal_load(&epsb[o]);
                outb[o] = lo;                       // normal stores: let L2
                outb[VD + o] = st;                  // merge 64B half-lines
                outb[2 * VD + o] = fmaf(st, ep, lo);
            }
        }
    }
}

extern "C" void kernel_launch(void* const* d_in, const int* in_sizes, int n_in,
                              void* d_out, int out_size, void* d_ws, size_t ws_size,
                              hipStream_t stream) {
    const float* vrepr = (const float*)d_in[0];
    const int*   sidx  = (const int*)d_in[1];
    const int*   tidx  = (const int*)d_in[2];
    const float* esgn  = (const float*)d_in[3];
    const float* enorm = (const float*)d_in[4];
    const float* loc_w = (const float*)d_in[5];
    const float* loc_b = (const float*)d_in[6];
    const float* std_w = (const float*)d_in[7];
    const float* std_b = (const float*)d_in[8];
    const float* eps   = (const float*)d_in[9];
    float* out = (float*)d_out;

    int E = in_sizes[1];
    int V = in_sizes[0] / D;

    char* ws = (char*)d_ws;
    size_t o = 0;
    unsigned short* vb   = (unsigned short*)(ws + o); o += (size_t)V * D * 2;
    unsigned short* ptrf = (unsigned short*)(ws + o); o += (size_t)V * D * 2;
    unsigned short* wTf  = (unsigned short*)(ws + o); o += (size_t)2 * D * D * 2;
    int* off  = (int*)(ws + o); o += ((size_t)V + 16) * sizeof(int);
    int* cnt  = (int*)(ws + o); o += ((size_t)V + 16) * sizeof(int);
    int* rank = (int*)(ws + o); o += (size_t)E * sizeof(int);
    int* bsum = (int*)(ws + o); o += 256 * sizeof(int);
    o = (o + 15) & ~(size_t)15;
    long long* pk = (long long*)(ws + o); o += (size_t)E * sizeof(long long);

    int nb = (V + 1023) >> 10;       // scan blocks (<=256)
    int n8 = V * (D / 8);
    int nvb = (n8 + 255) / 256;      // conv blocks
    int nwb = (2 * D * D + 1023) / 1024;  // weight-prep blocks (4 elems/thread)

    hipMemsetAsync(cnt, 0, (size_t)V * sizeof(int), stream);
    prep_conv_kernel<<<nvb + nwb, 256, 0, stream>>>(vrepr, loc_w, std_w, vb, wTf, n8, nvb);
    hist_kernel<<<(E + 255) / 256, 256, 0, stream>>>(tidx, cnt, rank, E);
    scan1_kernel<<<nb, 256, 0, stream>>>(cnt, bsum, V);
    scan2_kernel<<<1, 256, 0, stream>>>(bsum, nb);
    scan3_kernel<<<nb, 256, 0, stream>>>(cnt, bsum, off, V, E);
    fill_kernel<<<(E + 255) / 256, 256, 0, stream>>>(sidx, tidx, esgn, enorm, off, rank, pk, E);
    accum_kernel<<<(V * 64 + 255) / 256, 256, 0, stream>>>(vb, pk, off, ptrf, V);
    dim3 hgrid(2, (V + 63) / 64);
    head_mfma_kernel<<<hgrid, 256, 0, stream>>>(ptrf, wTf, loc_b, std_b, eps, out, V);
}